// Round 10
// baseline (607.969 us; speedup 1.0000x reference)
//
#include <hip/hip_runtime.h>
#include <hip/hip_bf16.h>

typedef __attribute__((ext_vector_type(8))) short short8;
typedef __attribute__((ext_vector_type(4))) float floatx4;
typedef __attribute__((ext_vector_type(4))) unsigned int uintx4;

// fast GELU: x * (1 - 1/(exp(2u)+1)), u = 0.79788456*(x + 0.044715 x^3)
__device__ __forceinline__ float gelu_fast(float x)
{
    float u = 0.7978845608f * x * (1.0f + 0.044715f * x * x);
    float e = __builtin_amdgcn_exp2f(2.885390082f * u);   // exp(2u)
    return x - x * __builtin_amdgcn_rcpf(e + 1.0f);
}

// prep: [0,T): count triangles per dst, record slot; [T,T+6144): fragment-
// ordered bf16 W (frag f=ko*8+nt over global ko 0..11, lane l: 8 elems
// W[ko*32+quad*8+j][nt*16+col]).
__global__ __launch_bounds__(256)
void prep(const float* __restrict__ Wg, uintx4* __restrict__ wq,
          const int* __restrict__ tri, int* __restrict__ cnt,
          int* __restrict__ slot, int T)
{
    int g = blockIdx.x * 256 + threadIdx.x;
    if (g < T) {
        int i2 = tri[g * 3 + 2];
        slot[g] = atomicAdd(&cnt[i2], 1);
    } else {
        int i = g - T;
        if (i < 6144) {
            int frag = i >> 6, lane = i & 63;
            int ko = frag >> 3, nt = frag & 7;
            int col = lane & 15, quad = lane >> 4;
            unsigned short tmp[8] __attribute__((aligned(16)));
#pragma unroll
            for (int j = 0; j < 8; ++j) {
                __hip_bfloat16 b =
                    __float2bfloat16(Wg[(ko * 32 + quad * 8 + j) * 128 + nt * 16 + col]);
                tmp[j] = *(unsigned short*)&b;
            }
            wq[i] = *(const uintx4*)tmp;
        }
    }
}

__device__ __forceinline__ int wave_incl_scan(int v, int lane)
{
#pragma unroll
    for (int o = 1; o < 64; o <<= 1) {
        int u = __shfl_up(v, o);
        if (lane >= o) v += u;
    }
    return v;
}

// Block-level exclusive scan of 1024 elements; writes per-element exclusive
// prefix (within block) and block total to partial[] (if non-null).
// Pass 1 (hist!=null, histx==null): also histogram the values into 64 bins
// (bucket = min(v,63)) via LDS-local counts + 64 global atomics per block.
// Pass 2 (histx!=null): single block; also exclusive-scan hist -> histx.
__global__ __launch_bounds__(1024)
void scan_blk(const int* __restrict__ in, int* __restrict__ outExcl,
              int* __restrict__ partial, int n,
              int* __restrict__ hist, int* __restrict__ histx)
{
    __shared__ int ws[16];
    __shared__ int lh[64];
    int t = threadIdx.x;
    int g = blockIdx.x * 1024 + t;
    int lane = t & 63, wv = t >> 6;
    int v = (g < n) ? in[g] : 0;
    int sc = wave_incl_scan(v, lane);
    if (lane == 63) ws[wv] = sc;
    if (hist && !histx && t < 64) lh[t] = 0;
    __syncthreads();
    if (wv == 0) {
        int b = (lane < 16) ? ws[lane] : 0;
        int bs = wave_incl_scan(b, lane);
        if (lane < 16) ws[lane] = bs;
    }
    if (hist && !histx && g < n) atomicAdd(&lh[v < 63 ? v : 63], 1);
    __syncthreads();
    int off = wv ? ws[wv - 1] : 0;
    if (g < n) outExcl[g] = off + sc - v;
    if (partial && t == 0) partial[blockIdx.x] = ws[15];
    if (hist && !histx && t < 64 && lh[t]) atomicAdd(&hist[t], lh[t]);
    if (histx && t < 64) {
        int hv = hist[t];
        int hs = wave_incl_scan(hv, lane);
        histx[t] = hs - hv;
    }
}

// Scatter triangles into dst-sorted order (pre-scaled byte offsets); also
// assign each edge a count-sorted rank (counting sort: histx base + cursor)
// and write sinfo[rank] = {start<<8 | min(c,255), row}. Zero-pad srec tail.
__global__ __launch_bounds__(256)
void scatter(const int* __restrict__ tri, const int* __restrict__ slot,
             const int* __restrict__ excl, const int* __restrict__ pscan,
             const int* __restrict__ cnt, int2* __restrict__ srec,
             const int* __restrict__ histx, int* __restrict__ histcur,
             int2* __restrict__ sinfo, int E, int T)
{
    int g = blockIdx.x * 256 + threadIdx.x;
    if (g < T) {
        int i0 = tri[g * 3 + 0];
        int i1 = tri[g * 3 + 1];
        int i2 = tri[g * 3 + 2];
        int pos = excl[i2] + pscan[i2 >> 10] + slot[g];
        srec[pos] = make_int2(i0 << 8, i1 << 8);   // byte offsets into G rows
    }
    if (g < E) {
        int c = cnt[g];
        int start = excl[g] + pscan[g >> 10];
        int cc = c < 63 ? c : 63;
        int rank = histx[cc] + atomicAdd(&histcur[cc], 1);
        sinfo[rank] = make_int2((start << 8) | (c < 255 ? c : 255), g);
    }
    if (g < 8)
        srec[T + g] = make_int2(0, 0);
}

// One-pass dense GEMM: all 3 W slices resident in 96KB LDS; A tile loaded and
// converted once, used for r=0,1,2. Output bf16, permuted C-layout (row i:
// physical elem col*8+nt = logical col nt*16+col). No barriers in main loop.
__global__ __launch_bounds__(1024, 1)
void edge_gemm(const float* __restrict__ fe_f, const uintx4* __restrict__ wq,
               unsigned short* __restrict__ G, int E)
{
    __shared__ uintx4 ldsW[6144];   // 96 KB: 12 global-ko x 8 nt fragment blocks

    const int tid  = threadIdx.x;
    const int wv   = tid >> 6;
    const int lane = tid & 63;
    const int col  = lane & 15;
    const int quad = lane >> 4;
    const int ntiles = (E + 15) >> 4;

    for (int i = tid; i < 6144; i += 1024) ldsW[i] = wq[i];
    __syncthreads();

#pragma unroll 1
    for (int tile = blockIdx.x * 16 + wv; tile < ntiles; tile += gridDim.x * 16) {
        int row_a = tile * 16 + col;
        if (row_a >= E) row_a = E - 1;
        const float* arow = fe_f + (size_t)row_a * 128 + quad * 8;

        floatx4 f[8];
#pragma unroll
        for (int l = 0; l < 8; ++l)
            f[l] = *(const floatx4*)(arow + (l >> 1) * 32 + (l & 1) * 4);

        short8 a[4];
#pragma unroll
        for (int ko = 0; ko < 4; ++ko) {
            unsigned short tmp[8] __attribute__((aligned(16)));
#pragma unroll
            for (int j = 0; j < 8; ++j) {
                __hip_bfloat16 b = __float2bfloat16(f[ko * 2 + (j >> 2)][j & 3]);
                tmp[j] = *(unsigned short*)&b;
            }
            a[ko] = *(const short8*)tmp;
        }

#pragma unroll 1
        for (int r = 0; r < 3; ++r) {
            floatx4 acc[8];
#pragma unroll
            for (int nt = 0; nt < 8; ++nt) acc[nt] = (floatx4)0.0f;

#pragma unroll
            for (int ko = 0; ko < 4; ++ko) {
#pragma unroll
                for (int nt = 0; nt < 8; ++nt) {
                    short8 bf = *(const short8*)&ldsW[r * 2048 + (ko * 8 + nt) * 64 + lane];
                    acc[nt] = __builtin_amdgcn_mfma_f32_16x16x32_bf16(a[ko], bf, acc[nt], 0, 0, 0);
                }
            }

            unsigned short* Gr = G + (size_t)r * E * 128;
#pragma unroll
            for (int rr = 0; rr < 4; ++rr) {
                int row = tile * 16 + quad * 4 + rr;
                if (row < E) {
                    unsigned short pk[8] __attribute__((aligned(16)));
#pragma unroll
                    for (int nt = 0; nt < 8; ++nt) {
                        __hip_bfloat16 hb = __float2bfloat16(acc[nt][rr]);
                        pk[nt] = *(unsigned short*)&hb;
                    }
                    *(uintx4*)(Gr + (size_t)row * 128 + col * 8) = *(const uintx4*)pk;
                }
            }
        }
    }
}

// Per-edge fused gather + GELU + mean + LayerNorm, QUARTER-WAVE rows over
// COUNT-SORTED ranks: 16 lanes per row, 4 rows per wave; groups of 4 rows
// have (near-)equal c, so the shared loop trip ceil(cmax/4) ~= ceil(c/4) --
// eliminates the ~27% padding from mixed-c groups and balances waves.
// One gather inst = 16B/lane = 4 full triangle row-reads; records fetched by
// lanes s&3 and distributed via __shfl (LDS pipe, off VMEM).
__global__ __launch_bounds__(256)
void mean_ln(const unsigned short* __restrict__ G, const int2* __restrict__ sinfo,
             const int* __restrict__ cnt, const int2* __restrict__ srec,
             const float* __restrict__ bias, const float* __restrict__ gamma,
             const float* __restrict__ beta, float* __restrict__ out, int E)
{
    const int tid  = threadIdx.x;
    const int lane = tid & 63;
    const int wid  = tid >> 6;
    const int h    = lane >> 4;    // quarter (row within group)
    const int s    = lane & 15;    // sub-lane within row

    const char* g0 = (const char*)G + s * 16;
    const char* g1 = g0 + (size_t)E * 256;
    const char* g2 = g1 + (size_t)E * 256;

    // params for j = k*16 + s (row-independent, hoisted out of group loop)
    float bv[8], gm[8], bt[8];
#pragma unroll
    for (int k = 0; k < 8; ++k) {
        bv[k] = bias[k * 16 + s];
        gm[k] = gamma[k * 16 + s];
        bt[k] = beta[k * 16 + s];
    }

    const int ngroups = (E + 3) >> 2;
    const int nwaves  = gridDim.x * 4;

    for (int grp = blockIdx.x * 4 + wid; grp < ngroups; grp += nwaves) {
        int rank = grp * 4 + h;
        int rk   = rank < E ? rank : E - 1;

        int2 si  = sinfo[rk];
        int row  = si.y;
        int c    = si.x & 255;
        int start = (int)((unsigned)si.x >> 8);
        if (__builtin_expect(c == 255, 0)) c = cnt[row];

        // cmax over the 4 quarters (~c after sorting)
        int cmax = max(c, __shfl_xor(c, 16));
        cmax = max(cmax, __shfl_xor(cmax, 32));

        // G2 row slice (16B = this lane's 8 cols) + bias -> base[8]
        uintx4 w2 = *(const uintx4*)(g2 + (size_t)row * 256);
        float base[8];
#pragma unroll
        for (int k = 0; k < 8; ++k) {
            unsigned int wv = (k & 1) ? (w2[k >> 1] & 0xffff0000u)
                                      : (w2[k >> 1] << 16);
            base[k] = __uint_as_float(wv) + bv[k];
        }

        float x[8];
#pragma unroll
        for (int k = 0; k < 8; ++k) x[k] = 0.0f;

        int cl = c - 1; if (cl < 0) cl = 0;
        for (int t = 0; t < cmax; t += 4) {
            // lanes s&3 of each quarter fetch records t..t+3 (clamped)
            int ci = t + (s & 3);
            if (ci > cl) ci = cl;
            int2 rr = srec[start + ci];
#pragma unroll
            for (int k = 0; k < 4; ++k) {
                unsigned int o0 = (unsigned)__shfl(rr.x, (h << 4) + k);
                unsigned int o1 = (unsigned)__shfl(rr.y, (h << 4) + k);
                uintx4 a = *(const uintx4*)(g0 + (size_t)o0);
                uintx4 b = *(const uintx4*)(g1 + (size_t)o1);
                bool ok = (t + k) < c;
#pragma unroll
                for (int p = 0; p < 8; ++p) {
                    unsigned int wa = (p & 1) ? (a[p >> 1] & 0xffff0000u)
                                              : (a[p >> 1] << 16);
                    unsigned int wb = (p & 1) ? (b[p >> 1] & 0xffff0000u)
                                              : (b[p >> 1] << 16);
                    float sv = __uint_as_float(wa) + __uint_as_float(wb) + base[p];
                    x[p] += ok ? gelu_fast(sv) : 0.0f;
                }
            }
        }

        // LayerNorm over this row's 128 cols (16 lanes x 8)
        float inv = 1.0f / fmaxf((float)c, 1.0f);
        float sm = 0.0f;
#pragma unroll
        for (int k = 0; k < 8; ++k) { x[k] *= inv; sm += x[k]; }
#pragma unroll
        for (int o = 8; o > 0; o >>= 1) sm += __shfl_xor(sm, o);
        float mu = sm * (1.0f / 128.0f);
        float vv = 0.0f;
#pragma unroll
        for (int k = 0; k < 8; ++k) { x[k] -= mu; vv += x[k] * x[k]; }
#pragma unroll
        for (int o = 8; o > 0; o >>= 1) vv += __shfl_xor(vv, o);
        float rstd = rsqrtf(vv * (1.0f / 128.0f) + 1e-5f);

        if (rank < E) {
            float* orow = out + (size_t)row * 128 + s;
#pragma unroll
            for (int k = 0; k < 8; ++k)
                __builtin_nontemporal_store(x[k] * rstd * gm[k] + bt[k],
                                            &orow[k * 16]);
        }
    }
}

extern "C" void kernel_launch(void* const* d_in, const int* in_sizes, int n_in,
                              void* d_out, int out_size, void* d_ws, size_t ws_size,
                              hipStream_t stream)
{
    const float* fe_f  = (const float*)d_in[0];
    const float* Wg    = (const float*)d_in[1];
    const float* bias  = (const float*)d_in[2];
    const float* gamma = (const float*)d_in[3];
    const float* beta  = (const float*)d_in[4];
    const int*   tri   = (const int*)d_in[5];

    int E = in_sizes[0] / 128;
    int T = in_sizes[5] / 3;

    // ws: G (3*E*128 bf16) | srec (T+8 int2) | wq (96KB) | slot (T i32) |
    //     cnt (E) | hist (64) | histcur (64) | histx (64) | excl (E) |
    //     partial (1024) | pscan (1024) | sinfo (E int2)
    unsigned short* G = (unsigned short*)d_ws;
    int2* srec = (int2*)((char*)d_ws + (size_t)3 * E * 256);
    uintx4* wq = (uintx4*)(srec + T + 8);
    int* slot = (int*)(wq + 6144);
    int* cnt  = slot + T;
    int* hist = cnt + E;
    int* histcur = hist + 64;
    int* histx = histcur + 64;
    int* excl = histx + 64;
    int* partial = excl + E;
    int* pscan = partial + 1024;
    int2* sinfo = (int2*)(pscan + 1024);

    // zero cnt + hist + histcur (contiguous)
    (void)hipMemsetAsync(cnt, 0, (size_t)E * sizeof(int) + 128 * sizeof(int),
                         stream);

    int total = T + 6144;
    prep<<<(total + 255) / 256, 256, 0, stream>>>(Wg, wq, tri, cnt, slot, T);

    int NB = (E + 1023) / 1024;   // 98 for E=100000 (must be <= 1024)
    scan_blk<<<NB, 1024, 0, stream>>>(cnt, excl, partial, E, hist, nullptr);
    scan_blk<<<1, 1024, 0, stream>>>(partial, pscan, nullptr, NB, hist, histx);

    scatter<<<(T + 255) / 256, 256, 0, stream>>>(tri, slot, excl, pscan, cnt,
                                                 srec, histx, histcur, sinfo,
                                                 E, T);

    edge_gemm<<<256, 1024, 0, stream>>>(fe_f, wq, G, E);

    mean_ln<<<2048, 256, 0, stream>>>(G, sinfo, cnt, srec, bias, gamma, beta,
                                      (float*)d_out, E);
}

// Round 11
// 209.471 us; speedup vs baseline: 2.9024x; 2.9024x over previous
//
#include <hip/hip_runtime.h>
#include <hip/hip_bf16.h>

typedef __attribute__((ext_vector_type(8))) short short8;
typedef __attribute__((ext_vector_type(4))) float floatx4;
typedef __attribute__((ext_vector_type(4))) unsigned int uintx4;

// fast GELU: x * (1 - 1/(exp(2u)+1)), u = 0.79788456*(x + 0.044715 x^3)
__device__ __forceinline__ float gelu_fast(float x)
{
    float u = 0.7978845608f * x * (1.0f + 0.044715f * x * x);
    float e = __builtin_amdgcn_exp2f(2.885390082f * u);   // exp(2u)
    return x - x * __builtin_amdgcn_rcpf(e + 1.0f);
}

// prep: [0,T): count triangles per dst, record slot; [T,T+6144): fragment-
// ordered bf16 W (frag f=ko*8+nt over global ko 0..11, lane l: 8 elems
// W[ko*32+quad*8+j][nt*16+col]).
__global__ __launch_bounds__(256)
void prep(const float* __restrict__ Wg, uintx4* __restrict__ wq,
          const int* __restrict__ tri, int* __restrict__ cnt,
          int* __restrict__ slot, int T)
{
    int g = blockIdx.x * 256 + threadIdx.x;
    if (g < T) {
        int i2 = tri[g * 3 + 2];
        slot[g] = atomicAdd(&cnt[i2], 1);
    } else {
        int i = g - T;
        if (i < 6144) {
            int frag = i >> 6, lane = i & 63;
            int ko = frag >> 3, nt = frag & 7;
            int col = lane & 15, quad = lane >> 4;
            unsigned short tmp[8] __attribute__((aligned(16)));
#pragma unroll
            for (int j = 0; j < 8; ++j) {
                __hip_bfloat16 b =
                    __float2bfloat16(Wg[(ko * 32 + quad * 8 + j) * 128 + nt * 16 + col]);
                tmp[j] = *(unsigned short*)&b;
            }
            wq[i] = *(const uintx4*)tmp;
        }
    }
}

__device__ __forceinline__ int wave_incl_scan(int v, int lane)
{
#pragma unroll
    for (int o = 1; o < 64; o <<= 1) {
        int u = __shfl_up(v, o);
        if (lane >= o) v += u;
    }
    return v;
}

// Block-level exclusive scan of 1024 elements; writes per-element exclusive
// prefix (within block) and block total to partial[] (if non-null).
// Pass 1 (hist!=null, histx==null): also histogram the values into 64 bins
// (bucket = min(v,63)) via LDS-local counts + 64 global atomics per block.
// Pass 2 (histx!=null): single block; also exclusive-scan hist -> histx.
__global__ __launch_bounds__(1024)
void scan_blk(const int* __restrict__ in, int* __restrict__ outExcl,
              int* __restrict__ partial, int n,
              int* __restrict__ hist, int* __restrict__ histx)
{
    __shared__ int ws[16];
    __shared__ int lh[64];
    int t = threadIdx.x;
    int g = blockIdx.x * 1024 + t;
    int lane = t & 63, wv = t >> 6;
    int v = (g < n) ? in[g] : 0;
    int sc = wave_incl_scan(v, lane);
    if (lane == 63) ws[wv] = sc;
    if (hist && !histx && t < 64) lh[t] = 0;
    __syncthreads();
    if (wv == 0) {
        int b = (lane < 16) ? ws[lane] : 0;
        int bs = wave_incl_scan(b, lane);
        if (lane < 16) ws[lane] = bs;
    }
    if (hist && !histx && g < n) atomicAdd(&lh[v < 63 ? v : 63], 1);
    __syncthreads();
    int off = wv ? ws[wv - 1] : 0;
    if (g < n) outExcl[g] = off + sc - v;
    if (partial && t == 0) partial[blockIdx.x] = ws[15];
    if (hist && !histx && t < 64 && lh[t]) atomicAdd(&hist[t], lh[t]);
    if (histx && t < 64) {
        int hv = hist[t];
        int hs = wave_incl_scan(hv, lane);
        histx[t] = hs - hv;
    }
}

// Scatter triangles into dst-sorted order (pre-scaled byte offsets); also
// assign each edge a count-sorted rank via BLOCK-AGGREGATED counting sort:
// LDS histogram gives each row an intra-block offset in its bin; ONE global
// value-returning atomicAdd per (block,bin) fetches the block base. This
// bounds same-address atomic contention at gridDim (~391), not ~20000 (the
// round-10 409us stall). sinfo[rank] = {start<<8 | min(c,255), row}.
__global__ __launch_bounds__(256)
void scatter(const int* __restrict__ tri, const int* __restrict__ slot,
             const int* __restrict__ excl, const int* __restrict__ pscan,
             const int* __restrict__ cnt, int2* __restrict__ srec,
             const int* __restrict__ histx, int* __restrict__ histcur,
             int2* __restrict__ sinfo, int E, int T)
{
    __shared__ int lcnt[64];
    __shared__ int lbase[64];
    int t = threadIdx.x;
    int g = blockIdx.x * 256 + t;

    if (t < 64) lcnt[t] = 0;
    __syncthreads();

    int cc = 0, lofs = 0, c = 0, start = 0;
    if (g < E) {
        c = cnt[g];
        start = excl[g] + pscan[g >> 10];
        cc = c < 63 ? c : 63;
        lofs = atomicAdd(&lcnt[cc], 1);
    }
    __syncthreads();
    if (t < 64 && lcnt[t]) lbase[t] = atomicAdd(&histcur[t], lcnt[t]);
    __syncthreads();
    if (g < E) {
        int rank = histx[cc] + lbase[cc] + lofs;
        sinfo[rank] = make_int2((start << 8) | (c < 255 ? c : 255), g);
    }

    if (g < T) {
        int i0 = tri[g * 3 + 0];
        int i1 = tri[g * 3 + 1];
        int i2 = tri[g * 3 + 2];
        int pos = excl[i2] + pscan[i2 >> 10] + slot[g];
        srec[pos] = make_int2(i0 << 8, i1 << 8);   // byte offsets into G rows
    }
    if (g < 8)
        srec[T + g] = make_int2(0, 0);
}

// One-pass dense GEMM: all 3 W slices resident in 96KB LDS; A tile loaded and
// converted once, used for r=0,1,2. Output bf16, permuted C-layout (row i:
// physical elem col*8+nt = logical col nt*16+col). No barriers in main loop.
__global__ __launch_bounds__(1024, 1)
void edge_gemm(const float* __restrict__ fe_f, const uintx4* __restrict__ wq,
               unsigned short* __restrict__ G, int E)
{
    __shared__ uintx4 ldsW[6144];   // 96 KB: 12 global-ko x 8 nt fragment blocks

    const int tid  = threadIdx.x;
    const int wv   = tid >> 6;
    const int lane = tid & 63;
    const int col  = lane & 15;
    const int quad = lane >> 4;
    const int ntiles = (E + 15) >> 4;

    for (int i = tid; i < 6144; i += 1024) ldsW[i] = wq[i];
    __syncthreads();

#pragma unroll 1
    for (int tile = blockIdx.x * 16 + wv; tile < ntiles; tile += gridDim.x * 16) {
        int row_a = tile * 16 + col;
        if (row_a >= E) row_a = E - 1;
        const float* arow = fe_f + (size_t)row_a * 128 + quad * 8;

        floatx4 f[8];
#pragma unroll
        for (int l = 0; l < 8; ++l)
            f[l] = *(const floatx4*)(arow + (l >> 1) * 32 + (l & 1) * 4);

        short8 a[4];
#pragma unroll
        for (int ko = 0; ko < 4; ++ko) {
            unsigned short tmp[8] __attribute__((aligned(16)));
#pragma unroll
            for (int j = 0; j < 8; ++j) {
                __hip_bfloat16 b = __float2bfloat16(f[ko * 2 + (j >> 2)][j & 3]);
                tmp[j] = *(unsigned short*)&b;
            }
            a[ko] = *(const short8*)tmp;
        }

#pragma unroll 1
        for (int r = 0; r < 3; ++r) {
            floatx4 acc[8];
#pragma unroll
            for (int nt = 0; nt < 8; ++nt) acc[nt] = (floatx4)0.0f;

#pragma unroll
            for (int ko = 0; ko < 4; ++ko) {
#pragma unroll
                for (int nt = 0; nt < 8; ++nt) {
                    short8 bf = *(const short8*)&ldsW[r * 2048 + (ko * 8 + nt) * 64 + lane];
                    acc[nt] = __builtin_amdgcn_mfma_f32_16x16x32_bf16(a[ko], bf, acc[nt], 0, 0, 0);
                }
            }

            unsigned short* Gr = G + (size_t)r * E * 128;
#pragma unroll
            for (int rr = 0; rr < 4; ++rr) {
                int row = tile * 16 + quad * 4 + rr;
                if (row < E) {
                    unsigned short pk[8] __attribute__((aligned(16)));
#pragma unroll
                    for (int nt = 0; nt < 8; ++nt) {
                        __hip_bfloat16 hb = __float2bfloat16(acc[nt][rr]);
                        pk[nt] = *(unsigned short*)&hb;
                    }
                    *(uintx4*)(Gr + (size_t)row * 128 + col * 8) = *(const uintx4*)pk;
                }
            }
        }
    }
}

// Per-edge fused gather + GELU + mean + LayerNorm, QUARTER-WAVE rows over
// COUNT-SORTED ranks: 16 lanes per row, 4 rows per wave; groups of 4 rows
// have (near-)equal c, so the shared loop trip ceil(cmax/4) ~= ceil(c/4) --
// eliminates the ~27% padding from mixed-c groups and balances waves.
// One gather inst = 16B/lane = 4 full triangle row-reads; records fetched by
// lanes s&3 and distributed via __shfl (LDS pipe, off VMEM).
__global__ __launch_bounds__(256)
void mean_ln(const unsigned short* __restrict__ G, const int2* __restrict__ sinfo,
             const int* __restrict__ cnt, const int2* __restrict__ srec,
             const float* __restrict__ bias, const float* __restrict__ gamma,
             const float* __restrict__ beta, float* __restrict__ out, int E)
{
    const int tid  = threadIdx.x;
    const int lane = tid & 63;
    const int wid  = tid >> 6;
    const int h    = lane >> 4;    // quarter (row within group)
    const int s    = lane & 15;    // sub-lane within row

    const char* g0 = (const char*)G + s * 16;
    const char* g1 = g0 + (size_t)E * 256;
    const char* g2 = g1 + (size_t)E * 256;

    // params for j = k*16 + s (row-independent, hoisted out of group loop)
    float bv[8], gm[8], bt[8];
#pragma unroll
    for (int k = 0; k < 8; ++k) {
        bv[k] = bias[k * 16 + s];
        gm[k] = gamma[k * 16 + s];
        bt[k] = beta[k * 16 + s];
    }

    const int ngroups = (E + 3) >> 2;
    const int nwaves  = gridDim.x * 4;

    for (int grp = blockIdx.x * 4 + wid; grp < ngroups; grp += nwaves) {
        int rank = grp * 4 + h;
        int rk   = rank < E ? rank : E - 1;

        int2 si  = sinfo[rk];
        int row  = si.y;
        int c    = si.x & 255;
        int start = (int)((unsigned)si.x >> 8);
        if (__builtin_expect(c == 255, 0)) c = cnt[row];

        // cmax over the 4 quarters (~c after sorting)
        int cmax = max(c, __shfl_xor(c, 16));
        cmax = max(cmax, __shfl_xor(cmax, 32));

        // G2 row slice (16B = this lane's 8 cols) + bias -> base[8]
        uintx4 w2 = *(const uintx4*)(g2 + (size_t)row * 256);
        float base[8];
#pragma unroll
        for (int k = 0; k < 8; ++k) {
            unsigned int wv = (k & 1) ? (w2[k >> 1] & 0xffff0000u)
                                      : (w2[k >> 1] << 16);
            base[k] = __uint_as_float(wv) + bv[k];
        }

        float x[8];
#pragma unroll
        for (int k = 0; k < 8; ++k) x[k] = 0.0f;

        int cl = c - 1; if (cl < 0) cl = 0;
        for (int t = 0; t < cmax; t += 4) {
            // lanes s&3 of each quarter fetch records t..t+3 (clamped)
            int ci = t + (s & 3);
            if (ci > cl) ci = cl;
            int2 rr = srec[start + ci];
#pragma unroll
            for (int k = 0; k < 4; ++k) {
                unsigned int o0 = (unsigned)__shfl(rr.x, (h << 4) + k);
                unsigned int o1 = (unsigned)__shfl(rr.y, (h << 4) + k);
                uintx4 a = *(const uintx4*)(g0 + (size_t)o0);
                uintx4 b = *(const uintx4*)(g1 + (size_t)o1);
                bool ok = (t + k) < c;
#pragma unroll
                for (int p = 0; p < 8; ++p) {
                    unsigned int wa = (p & 1) ? (a[p >> 1] & 0xffff0000u)
                                              : (a[p >> 1] << 16);
                    unsigned int wb = (p & 1) ? (b[p >> 1] & 0xffff0000u)
                                              : (b[p >> 1] << 16);
                    float sv = __uint_as_float(wa) + __uint_as_float(wb) + base[p];
                    x[p] += ok ? gelu_fast(sv) : 0.0f;
                }
            }
        }

        // LayerNorm over this row's 128 cols (16 lanes x 8)
        float inv = 1.0f / fmaxf((float)c, 1.0f);
        float sm = 0.0f;
#pragma unroll
        for (int k = 0; k < 8; ++k) { x[k] *= inv; sm += x[k]; }
#pragma unroll
        for (int o = 8; o > 0; o >>= 1) sm += __shfl_xor(sm, o);
        float mu = sm * (1.0f / 128.0f);
        float vv = 0.0f;
#pragma unroll
        for (int k = 0; k < 8; ++k) { x[k] -= mu; vv += x[k] * x[k]; }
#pragma unroll
        for (int o = 8; o > 0; o >>= 1) vv += __shfl_xor(vv, o);
        float rstd = rsqrtf(vv * (1.0f / 128.0f) + 1e-5f);

        if (rank < E) {
            float* orow = out + (size_t)row * 128 + s;
#pragma unroll
            for (int k = 0; k < 8; ++k)
                __builtin_nontemporal_store(x[k] * rstd * gm[k] + bt[k],
                                            &orow[k * 16]);
        }
    }
}

extern "C" void kernel_launch(void* const* d_in, const int* in_sizes, int n_in,
                              void* d_out, int out_size, void* d_ws, size_t ws_size,
                              hipStream_t stream)
{
    const float* fe_f  = (const float*)d_in[0];
    const float* Wg    = (const float*)d_in[1];
    const float* bias  = (const float*)d_in[2];
    const float* gamma = (const float*)d_in[3];
    const float* beta  = (const float*)d_in[4];
    const int*   tri   = (const int*)d_in[5];

    int E = in_sizes[0] / 128;
    int T = in_sizes[5] / 3;

    // ws: G (3*E*128 bf16) | srec (T+8 int2) | wq (96KB) | slot (T i32) |
    //     cnt (E) | hist (64) | histcur (64) | histx (64) | excl (E) |
    //     partial (1024) | pscan (1024) | sinfo (E int2)
    unsigned short* G = (unsigned short*)d_ws;
    int2* srec = (int2*)((char*)d_ws + (size_t)3 * E * 256);
    uintx4* wq = (uintx4*)(srec + T + 8);
    int* slot = (int*)(wq + 6144);
    int* cnt  = slot + T;
    int* hist = cnt + E;
    int* histcur = hist + 64;
    int* histx = histcur + 64;
    int* excl = histx + 64;
    int* partial = excl + E;
    int* pscan = partial + 1024;
    int2* sinfo = (int2*)(pscan + 1024);

    // zero cnt + hist + histcur (contiguous)
    (void)hipMemsetAsync(cnt, 0, (size_t)E * sizeof(int) + 128 * sizeof(int),
                         stream);

    int total = T + 6144;
    prep<<<(total + 255) / 256, 256, 0, stream>>>(Wg, wq, tri, cnt, slot, T);

    int NB = (E + 1023) / 1024;   // 98 for E=100000 (must be <= 1024)
    scan_blk<<<NB, 1024, 0, stream>>>(cnt, excl, partial, E, hist, nullptr);
    scan_blk<<<1, 1024, 0, stream>>>(partial, pscan, nullptr, NB, hist, histx);

    scatter<<<(T + 255) / 256, 256, 0, stream>>>(tri, slot, excl, pscan, cnt,
                                                 srec, histx, histcur, sinfo,
                                                 E, T);

    edge_gemm<<<256, 1024, 0, stream>>>(fe_f, wq, G, E);

    mean_ln<<<2048, 256, 0, stream>>>(G, sinfo, cnt, srec, bias, gamma, beta,
                                      (float*)d_out, E);
}

// Round 12
// 200.664 us; speedup vs baseline: 3.0298x; 1.0439x over previous
//
#include <hip/hip_runtime.h>
#include <hip/hip_bf16.h>

typedef __attribute__((ext_vector_type(8))) short short8;
typedef __attribute__((ext_vector_type(4))) float floatx4;
typedef __attribute__((ext_vector_type(4))) unsigned int uintx4;

#define GEMM_BLOCKS 256

// fast GELU: x * (1 - 1/(exp(2u)+1)), u = 0.79788456*(x + 0.044715 x^3)
__device__ __forceinline__ float gelu_fast(float x)
{
    float u = 0.7978845608f * x * (1.0f + 0.044715f * x * x);
    float e = __builtin_amdgcn_exp2f(2.885390082f * u);   // exp(2u)
    return x - x * __builtin_amdgcn_rcpf(e + 1.0f);
}

// prep: [0,T): count triangles per dst, record slot; [T,T+6144): fragment-
// ordered bf16 W (frag f=ko*8+nt over global ko 0..11, lane l: 8 elems
// W[ko*32+quad*8+j][nt*16+col]).
__global__ __launch_bounds__(256)
void prep(const float* __restrict__ Wg, uintx4* __restrict__ wq,
          const int* __restrict__ tri, int* __restrict__ cnt,
          int* __restrict__ slot, int T)
{
    int g = blockIdx.x * 256 + threadIdx.x;
    if (g < T) {
        int i2 = tri[g * 3 + 2];
        slot[g] = atomicAdd(&cnt[i2], 1);
    } else {
        int i = g - T;
        if (i < 6144) {
            int frag = i >> 6, lane = i & 63;
            int ko = frag >> 3, nt = frag & 7;
            int col = lane & 15, quad = lane >> 4;
            unsigned short tmp[8] __attribute__((aligned(16)));
#pragma unroll
            for (int j = 0; j < 8; ++j) {
                __hip_bfloat16 b =
                    __float2bfloat16(Wg[(ko * 32 + quad * 8 + j) * 128 + nt * 16 + col]);
                tmp[j] = *(unsigned short*)&b;
            }
            wq[i] = *(const uintx4*)tmp;
        }
    }
}

__device__ __forceinline__ int wave_incl_scan(int v, int lane)
{
#pragma unroll
    for (int o = 1; o < 64; o <<= 1) {
        int u = __shfl_up(v, o);
        if (lane >= o) v += u;
    }
    return v;
}

// Block-level exclusive scan of 1024 elements; per-element exclusive prefix,
// block total to partial[], and 64-bin count histogram (bucket=min(v,63)).
__global__ __launch_bounds__(1024)
void scan_blk(const int* __restrict__ in, int* __restrict__ outExcl,
              int* __restrict__ partial, int n, int* __restrict__ hist)
{
    __shared__ int ws[16];
    __shared__ int lh[64];
    int t = threadIdx.x;
    int g = blockIdx.x * 1024 + t;
    int lane = t & 63, wv = t >> 6;
    int v = (g < n) ? in[g] : 0;
    int sc = wave_incl_scan(v, lane);
    if (lane == 63) ws[wv] = sc;
    if (t < 64) lh[t] = 0;
    __syncthreads();
    if (wv == 0) {
        int b = (lane < 16) ? ws[lane] : 0;
        int bs = wave_incl_scan(b, lane);
        if (lane < 16) ws[lane] = bs;
    }
    if (g < n) atomicAdd(&lh[v < 63 ? v : 63], 1);
    __syncthreads();
    int off = wv ? ws[wv - 1] : 0;
    if (g < n) outExcl[g] = off + sc - v;
    if (t == 0) partial[blockIdx.x] = ws[15];
    if (t < 64 && lh[t]) atomicAdd(&hist[t], lh[t]);
}

// Fused kernel: blocks [0,GEMM_BLOCKS) run the one-pass dense GEMM (all 3 W
// slices in 96KB LDS, A loaded/converted once per tile, bf16 permuted-C out);
// blocks [GEMM_BLOCKS,..) run scatter at 1024 threads: per-block redundant
// in-LDS scans of partial[] (pscan) and hist[] (histx) replace the old scan2
// dispatch; block-aggregated counting-sort rank; srec + sinfo writes.
// Both halves depend only on {prep, scan1} -> safe in one dispatch.
__global__ __launch_bounds__(1024, 1)
void gemm_scatter(const float* __restrict__ fe_f, const uintx4* __restrict__ wq,
                  unsigned short* __restrict__ G, const int* __restrict__ tri,
                  const int* __restrict__ slot, const int* __restrict__ excl,
                  const int* __restrict__ partial, const int* __restrict__ hist,
                  int* __restrict__ histcur, const int* __restrict__ cnt,
                  int2* __restrict__ srec, int2* __restrict__ sinfo,
                  int E, int T, int NB)
{
    __shared__ uintx4 ldsW[6144];   // 96 KB (gemm blocks only)
    __shared__ int ps[128];         // pscan (NB <= 128)
    __shared__ int hx[64];          // hist exclusive scan
    __shared__ int ws[16];
    __shared__ int lcnt[64];
    __shared__ int lbase[64];

    const int tid = threadIdx.x;

    if (blockIdx.x < GEMM_BLOCKS) {
        const int wv   = tid >> 6;
        const int lane = tid & 63;
        const int col  = lane & 15;
        const int quad = lane >> 4;
        const int ntiles = (E + 15) >> 4;

        for (int i = tid; i < 6144; i += 1024) ldsW[i] = wq[i];
        __syncthreads();

#pragma unroll 1
        for (int tile = blockIdx.x * 16 + wv; tile < ntiles;
             tile += GEMM_BLOCKS * 16) {
            int row_a = tile * 16 + col;
            if (row_a >= E) row_a = E - 1;
            const float* arow = fe_f + (size_t)row_a * 128 + quad * 8;

            floatx4 f[8];
#pragma unroll
            for (int l = 0; l < 8; ++l)
                f[l] = *(const floatx4*)(arow + (l >> 1) * 32 + (l & 1) * 4);

            short8 a[4];
#pragma unroll
            for (int ko = 0; ko < 4; ++ko) {
                unsigned short tmp[8] __attribute__((aligned(16)));
#pragma unroll
                for (int j = 0; j < 8; ++j) {
                    __hip_bfloat16 b = __float2bfloat16(f[ko * 2 + (j >> 2)][j & 3]);
                    tmp[j] = *(unsigned short*)&b;
                }
                a[ko] = *(const short8*)tmp;
            }

#pragma unroll 1
            for (int r = 0; r < 3; ++r) {
                floatx4 acc[8];
#pragma unroll
                for (int nt = 0; nt < 8; ++nt) acc[nt] = (floatx4)0.0f;

#pragma unroll
                for (int ko = 0; ko < 4; ++ko) {
#pragma unroll
                    for (int nt = 0; nt < 8; ++nt) {
                        short8 bf = *(const short8*)&ldsW[r * 2048 + (ko * 8 + nt) * 64 + lane];
                        acc[nt] = __builtin_amdgcn_mfma_f32_16x16x32_bf16(a[ko], bf, acc[nt], 0, 0, 0);
                    }
                }

                unsigned short* Gr = G + (size_t)r * E * 128;
#pragma unroll
                for (int rr = 0; rr < 4; ++rr) {
                    int row = tile * 16 + quad * 4 + rr;
                    if (row < E) {
                        unsigned short pk[8] __attribute__((aligned(16)));
#pragma unroll
                        for (int nt = 0; nt < 8; ++nt) {
                            __hip_bfloat16 hb = __float2bfloat16(acc[nt][rr]);
                            pk[nt] = *(unsigned short*)&hb;
                        }
                        *(uintx4*)(Gr + (size_t)row * 128 + col * 8) = *(const uintx4*)pk;
                    }
                }
            }
        }
    } else {
        const int lane = tid & 63, w = tid >> 6;

        // in-LDS pscan over partial[0..NB) (block scan, NB<=128)
        int v = (tid < NB) ? partial[tid] : 0;
        int sc = wave_incl_scan(v, lane);
        if (lane == 63) ws[w] = sc;
        if (tid < 64) lcnt[tid] = 0;
        __syncthreads();
        if (w == 0) {
            int b = (lane < 16) ? ws[lane] : 0;
            int bs = wave_incl_scan(b, lane);
            if (lane < 16) ws[lane] = bs;
            // hist exclusive scan (64 bins)
            int hv = hist[lane];
            int hs = wave_incl_scan(hv, lane);
            hx[lane] = hs - hv;
        }
        __syncthreads();
        int off = w ? ws[w - 1] : 0;
        if (tid < NB && tid < 128) ps[tid] = off + sc - v;
        __syncthreads();

        int g = (blockIdx.x - GEMM_BLOCKS) * 1024 + tid;

        int cc = 0, lofs = 0, c = 0, start = 0;
        if (g < E) {
            c = cnt[g];
            start = excl[g] + ps[g >> 10];
            cc = c < 63 ? c : 63;
            lofs = atomicAdd(&lcnt[cc], 1);
        }
        __syncthreads();
        if (tid < 64 && lcnt[tid]) lbase[tid] = atomicAdd(&histcur[tid], lcnt[tid]);
        __syncthreads();
        if (g < E) {
            int rank = hx[cc] + lbase[cc] + lofs;
            sinfo[rank] = make_int2((start << 8) | (c < 255 ? c : 255), g);
        }

        if (g < T) {
            int i0 = tri[g * 3 + 0];
            int i1 = tri[g * 3 + 1];
            int i2 = tri[g * 3 + 2];
            int pos = excl[i2] + ps[i2 >> 10] + slot[g];
            srec[pos] = make_int2(i0 << 8, i1 << 8);   // byte offsets into G rows
        }
        if (g < 8)
            srec[T + g] = make_int2(0, 0);
    }
}

// Per-edge fused gather + GELU + mean + LayerNorm, QUARTER-WAVE rows over
// COUNT-SORTED ranks (16 lanes/row, 4 rows/wave, equal-c groups). Adds:
// sinfo prefetch across the grid-stride loop (hides ~300cy/group) and
// mask-FMA accumulate (1 cndmask + 8 fma vs 8 cndmask + 8 add per k).
__global__ __launch_bounds__(256)
void mean_ln(const unsigned short* __restrict__ G, const int2* __restrict__ sinfo,
             const int* __restrict__ cnt, const int2* __restrict__ srec,
             const float* __restrict__ bias, const float* __restrict__ gamma,
             const float* __restrict__ beta, float* __restrict__ out, int E)
{
    const int tid  = threadIdx.x;
    const int lane = tid & 63;
    const int wid  = tid >> 6;
    const int h    = lane >> 4;    // quarter (row within group)
    const int s    = lane & 15;    // sub-lane within row

    const char* g0 = (const char*)G + s * 16;
    const char* g1 = g0 + (size_t)E * 256;
    const char* g2 = g1 + (size_t)E * 256;

    float bv[8], gm[8], bt[8];
#pragma unroll
    for (int k = 0; k < 8; ++k) {
        bv[k] = bias[k * 16 + s];
        gm[k] = gamma[k * 16 + s];
        bt[k] = beta[k * 16 + s];
    }

    const int ngroups = (E + 3) >> 2;
    const int nwaves  = gridDim.x * 4;

    int grp = blockIdx.x * 4 + wid;
    if (grp >= ngroups) return;
    int rk0 = grp * 4 + h;
    if (rk0 >= E) rk0 = E - 1;
    int2 si = sinfo[rk0];

    for (; grp < ngroups; grp += nwaves) {
        // prefetch next group's sinfo before the heavy body
        int gn = grp + nwaves;
        int rkn = gn * 4 + h;
        if (rkn >= E) rkn = E - 1;
        int2 si_nx = (gn < ngroups) ? sinfo[rkn] : si;

        int rank = grp * 4 + h;
        int row  = si.y;
        int c    = si.x & 255;
        int start = (int)((unsigned)si.x >> 8);
        if (__builtin_expect(c == 255, 0)) c = cnt[row];

        int cmax = max(c, __shfl_xor(c, 16));
        cmax = max(cmax, __shfl_xor(cmax, 32));

        uintx4 w2 = *(const uintx4*)(g2 + (size_t)row * 256);
        float base[8];
#pragma unroll
        for (int k = 0; k < 8; ++k) {
            unsigned int wv = (k & 1) ? (w2[k >> 1] & 0xffff0000u)
                                      : (w2[k >> 1] << 16);
            base[k] = __uint_as_float(wv) + bv[k];
        }

        float x[8];
#pragma unroll
        for (int k = 0; k < 8; ++k) x[k] = 0.0f;

        int cl = c - 1; if (cl < 0) cl = 0;
        for (int t = 0; t < cmax; t += 4) {
            int ci = t + (s & 3);
            if (ci > cl) ci = cl;
            int2 rr = srec[start + ci];
#pragma unroll
            for (int k = 0; k < 4; ++k) {
                unsigned int o0 = (unsigned)__shfl(rr.x, (h << 4) + k);
                unsigned int o1 = (unsigned)__shfl(rr.y, (h << 4) + k);
                uintx4 a = *(const uintx4*)(g0 + (size_t)o0);
                uintx4 b = *(const uintx4*)(g1 + (size_t)o1);
                float mk = (t + k) < c ? 1.0f : 0.0f;
#pragma unroll
                for (int p = 0; p < 8; ++p) {
                    unsigned int wa = (p & 1) ? (a[p >> 1] & 0xffff0000u)
                                              : (a[p >> 1] << 16);
                    unsigned int wb = (p & 1) ? (b[p >> 1] & 0xffff0000u)
                                              : (b[p >> 1] << 16);
                    float sv = __uint_as_float(wa) + __uint_as_float(wb) + base[p];
                    x[p] = __builtin_fmaf(mk, gelu_fast(sv), x[p]);
                }
            }
        }

        float inv = 1.0f / fmaxf((float)c, 1.0f);
        float sm = 0.0f;
#pragma unroll
        for (int k = 0; k < 8; ++k) { x[k] *= inv; sm += x[k]; }
#pragma unroll
        for (int o = 8; o > 0; o >>= 1) sm += __shfl_xor(sm, o);
        float mu = sm * (1.0f / 128.0f);
        float vv = 0.0f;
#pragma unroll
        for (int k = 0; k < 8; ++k) { x[k] -= mu; vv += x[k] * x[k]; }
#pragma unroll
        for (int o = 8; o > 0; o >>= 1) vv += __shfl_xor(vv, o);
        float rstd = rsqrtf(vv * (1.0f / 128.0f) + 1e-5f);

        if (rank < E) {
            float* orow = out + (size_t)row * 128 + s;
#pragma unroll
            for (int k = 0; k < 8; ++k)
                __builtin_nontemporal_store(x[k] * rstd * gm[k] + bt[k],
                                            &orow[k * 16]);
        }
        si = si_nx;
    }
}

extern "C" void kernel_launch(void* const* d_in, const int* in_sizes, int n_in,
                              void* d_out, int out_size, void* d_ws, size_t ws_size,
                              hipStream_t stream)
{
    const float* fe_f  = (const float*)d_in[0];
    const float* Wg    = (const float*)d_in[1];
    const float* bias  = (const float*)d_in[2];
    const float* gamma = (const float*)d_in[3];
    const float* beta  = (const float*)d_in[4];
    const int*   tri   = (const int*)d_in[5];

    int E = in_sizes[0] / 128;
    int T = in_sizes[5] / 3;

    // ws: G (3*E*128 bf16) | srec (T+8 int2) | wq (96KB) | slot (T i32) |
    //     cnt (E) | hist (64) | histcur (64) | pad (64) | excl (E) |
    //     partial (1024) | sinfo (E int2)
    unsigned short* G = (unsigned short*)d_ws;
    int2* srec = (int2*)((char*)d_ws + (size_t)3 * E * 256);
    uintx4* wq = (uintx4*)(srec + T + 8);
    int* slot = (int*)(wq + 6144);
    int* cnt  = slot + T;
    int* hist = cnt + E;
    int* histcur = hist + 64;
    int* excl = histcur + 128;   // 64 pad
    int* partial = excl + E;
    int2* sinfo = (int2*)(partial + 1024);

    // zero cnt + hist + histcur (contiguous)
    (void)hipMemsetAsync(cnt, 0, (size_t)E * sizeof(int) + 128 * sizeof(int),
                         stream);

    int total = T + 6144;
    prep<<<(total + 255) / 256, 256, 0, stream>>>(Wg, wq, tri, cnt, slot, T);

    int NB = (E + 1023) / 1024;   // 98 for E=100000 (must be <= 128)
    scan_blk<<<NB, 1024, 0, stream>>>(cnt, excl, partial, E, hist);

    int SB = (T + 1023) / 1024;   // scatter blocks (1024 threads each)
    gemm_scatter<<<GEMM_BLOCKS + SB, 1024, 0, stream>>>(
        fe_f, wq, G, tri, slot, excl, partial, hist, histcur, cnt,
        srec, sinfo, E, T, NB);

    mean_ln<<<2048, 256, 0, stream>>>(G, sinfo, cnt, srec, bias, gamma, beta,
                                      (float*)d_out, E);
}